// Round 2
// baseline (2451.675 us; speedup 1.0000x reference)
//
#include <hip/hip_runtime.h>
#include <hip/hip_bf16.h>

typedef unsigned int u32;
typedef unsigned short u16;

// Problem constants
#define NWORDS 4096   // B*S
#define CC 32         // chars per word
#define EE 128        // embed dim
#define HHH 256       // hidden
#define GG 768        // 3*H
#define MM 16         // words per block
#define VOCABN 262

// Workspace layout (float/u32 units). ws[0] = dtype flag (1 = fp32 inputs, 0 = bf16).
#define IH_F (EE*GG)                        // 98304 floats per W_ih (transposed [k][768])
#define HH_F (HHH*GG)                       // 196608 floats per W_hh
#define WT_OFF 16
#define BIAS_OFF (WT_OFF + 2*(IH_F+HH_F))   // 589840 : bih_fw, bhh_fw, bih_bw, bhh_bw (768 each)
#define EMB_OFF (BIAS_OFF + 4*GG)           // 592912 : embed fp32 [262][128]
#define EMB_N (VOCABN*EE)                   // 33536
#define MISC_N (EMB_N + 4*GG)               // 36608

__device__ __forceinline__ float bf1(u16 u){ union{u32 i; float f;} v; v.i = ((u32)u) << 16; return v.f; }
__device__ __forceinline__ float loadf(const void* p, int i, u32 isf){
  return isf ? ((const float*)p)[i] : bf1(((const u16*)p)[i]);
}

__device__ __forceinline__ float sigmoid_f(float x){
  float e = __builtin_amdgcn_exp2f(-1.4426950408889634f * x);
  return __builtin_amdgcn_rcpf(1.0f + e);
}
__device__ __forceinline__ float tanh_f(float x){
  float ax = __builtin_fabsf(x);
  float e  = __builtin_amdgcn_exp2f(-2.8853900817779268f * ax);
  float t  = 1.0f - 2.0f * e * __builtin_amdgcn_rcpf(1.0f + e);
  return __builtin_copysignf(t, x);
}

// ---- dtype probe: low 16 bits of fp32 mantissas look like huge/NaN bf16s ----
__global__ void detect_k(const u32* __restrict__ emb_raw, u32* __restrict__ flag){
  int lane = threadIdx.x;   // 64 threads
  int bad = 0;
  for (int i = lane; i < 256; i += 64) {
    float f = bf1((u16)(emb_raw[i] & 0xFFFFu));
    if (!(__builtin_fabsf(f) <= 64.0f)) bad = 1;   // catches NaN too (compare is false)
  }
  unsigned long long m = __ballot(bad);
  if (lane == 0) flag[0] = (m != 0ull) ? 1u : 0u;
}

// ---- canonicalize weights: transpose to fp32 [k][768] per matrix ----
__global__ void prep_weights(const void* __restrict__ Wih_fw, const void* __restrict__ Whh_fw,
                             const void* __restrict__ Wih_bw, const void* __restrict__ Whh_bw,
                             float* __restrict__ ws)
{
  const u32 isf = ((const u32*)ws)[0];
  int i = blockIdx.x * 256 + threadIdx.x;         // grid sized exactly: 2*(IH_F+HH_F)
  const void* W; int base, K;
  if (i < IH_F)                 { W = Wih_fw; base = 0;            K = EE;  }
  else if (i < IH_F + HH_F)     { W = Whh_fw; base = IH_F;         K = HHH; }
  else if (i < 2*IH_F + HH_F)   { W = Wih_bw; base = IH_F + HH_F;  K = EE;  }
  else                          { W = Whh_bw; base = 2*IH_F+HH_F;  K = HHH; }
  int loc = i - base;
  int k   = loc / GG;
  int g   = loc - k * GG;
  ws[WT_OFF + i] = loadf(W, g*K + k, isf);
}

// ---- canonicalize embed table + biases to fp32 ----
__global__ void prep_misc(const void* __restrict__ embed,
                          const void* __restrict__ b0, const void* __restrict__ b1,
                          const void* __restrict__ b2, const void* __restrict__ b3,
                          float* __restrict__ ws)
{
  const u32 isf = ((const u32*)ws)[0];
  int i = blockIdx.x * 256 + threadIdx.x;         // grid sized exactly: MISC_N
  if (i < EMB_N) {
    ws[EMB_OFF + i] = loadf(embed, i, isf);
  } else {
    int loc = i - EMB_N;
    int b = loc / GG, o = loc - b * GG;
    const void* src = (b == 0) ? b0 : (b == 1) ? b1 : (b == 2) ? b2 : b3;
    ws[BIAS_OFF + loc] = loadf(src, o, isf);
  }
}

// Accumulate 3 gate dot-products over kdim for 16 words.
// wt: fp32 transposed weights [k][768]; src: LDS [16][stride] fp32.
__device__ __forceinline__ void accum(const float* __restrict__ wt, int j,
                                      const float* src, int stride, int nch,
                                      float* acc_r, float* acc_z, float* acc_n)
{
  const float* p = wt + j;
  for (int c = 0; c < nch; ++c) {          // each chunk = 4 k values
    float wr0 = p[0],        wz0 = p[256],        wn0 = p[512];
    float wr1 = p[GG],       wz1 = p[GG+256],     wn1 = p[GG+512];
    float wr2 = p[2*GG],     wz2 = p[2*GG+256],   wn2 = p[2*GG+512];
    float wr3 = p[3*GG],     wz3 = p[3*GG+256],   wn3 = p[3*GG+512];
    p += 4*GG;
    const float* s = src + 4*c;
    #pragma unroll
    for (int w = 0; w < MM; ++w) {
      float4 xv = *reinterpret_cast<const float4*>(s + w*stride);  // LDS broadcast
      acc_r[w] = fmaf(xv.w, wr3, fmaf(xv.z, wr2, fmaf(xv.y, wr1, fmaf(xv.x, wr0, acc_r[w]))));
      acc_z[w] = fmaf(xv.w, wz3, fmaf(xv.z, wz2, fmaf(xv.y, wz1, fmaf(xv.x, wz0, acc_z[w]))));
      acc_n[w] = fmaf(xv.w, wn3, fmaf(xv.z, wn2, fmaf(xv.y, wn1, fmaf(xv.x, wn0, acc_n[w]))));
    }
  }
}

__global__ __launch_bounds__(256, 2)
void gru_kernel(const int* __restrict__ chars, const int* __restrict__ chars_mask,
                const int* __restrict__ data_mask, const float* __restrict__ ws,
                void* __restrict__ out)
{
  const u32 is_fp32 = ((const u32*)ws)[0];
  const int dir = blockIdx.y;
  const float* wt_ih = ws + WT_OFF + (dir ? (IH_F + HH_F) : 0);
  const float* wt_hh = wt_ih + IH_F;
  const float* bih   = ws + BIAS_OFF + dir*2*GG;
  const float* bhh   = bih + GG;
  const float* emb   = ws + EMB_OFF;

  __shared__ __align__(16) float sh_h[MM][HHH];  // 16 KB
  __shared__ __align__(16) float sh_x[MM][EE];   // 8 KB
  __shared__ float sh_m[MM];

  const int j = threadIdx.x;          // output channel 0..255
  const int word0 = blockIdx.x * MM;

  #pragma unroll
  for (int w = 0; w < MM; ++w) sh_h[w][j] = 0.0f;

  const float bias_r  = bih[j]       + bhh[j];
  const float bias_z  = bih[256 + j] + bhh[256 + j];
  const float bias_xn = bih[512 + j];
  const float bias_hn = bhh[512 + j];

  const int wx   = j >> 4;   // word this thread stages x for
  const int part = j & 15;   // 8-float chunk within embed row

  #pragma unroll 1
  for (int s = 0; s < CC; ++s) {
    const int t = dir ? (CC - 1 - s) : s;   // reverse scan for bw direction
    __syncthreads();  // prev step's h writes visible; prev x reads done
    {
      // stage x_t: 16 words x 128 dims from canonical fp32 embed
      int ci = chars[(word0 + wx)*CC + t];
      const float* erow = emb + (size_t)ci*EE + part*8;
      float4 f0 = *reinterpret_cast<const float4*>(erow);
      float4 f1 = *reinterpret_cast<const float4*>(erow + 4);
      *reinterpret_cast<float4*>(&sh_x[wx][part*8])     = f0;
      *reinterpret_cast<float4*>(&sh_x[wx][part*8 + 4]) = f1;
      if (j < MM) sh_m[j] = (float)chars_mask[(word0 + j)*CC + t];
    }
    __syncthreads();  // x staged

    float acc_r[MM], acc_z[MM], acc_xn[MM], acc_hn[MM];
    #pragma unroll
    for (int w = 0; w < MM; ++w) {
      acc_r[w] = bias_r; acc_z[w] = bias_z; acc_xn[w] = bias_xn; acc_hn[w] = bias_hn;
    }

    accum(wt_ih, j, &sh_x[0][0], EE,  EE/4,  acc_r, acc_z, acc_xn);  // x @ W_ih^T
    accum(wt_hh, j, &sh_h[0][0], HHH, HHH/4, acc_r, acc_z, acc_hn);  // h @ W_hh^T

    __syncthreads();  // all reads of old h done before writes
    #pragma unroll
    for (int w = 0; w < MM; ++w) {
      float r = sigmoid_f(acc_r[w]);
      float z = sigmoid_f(acc_z[w]);
      float n = tanh_f(fmaf(r, acc_hn[w], acc_xn[w]));
      float hold = sh_h[w][j];
      float hnew = fmaf(z, hold - n, n);              // (1-z)*n + z*h
      sh_h[w][j] = fmaf(sh_m[w], hnew - hold, hold);  // mask freeze (m is exactly 0/1)
    }
  }
  __syncthreads();

  #pragma unroll
  for (int w = 0; w < MM; ++w) {
    const int word = word0 + w;
    float v = sh_h[w][j] * (float)data_mask[word];
    size_t idx = (size_t)word*(2*HHH) + dir*HHH + j;
    if (is_fp32) ((float*)out)[idx] = v;
    else ((__hip_bfloat16*)out)[idx] = __float2bfloat16(v);
  }
}

extern "C" void kernel_launch(void* const* d_in, const int* in_sizes, int n_in,
                              void* d_out, int out_size, void* d_ws, size_t ws_size,
                              hipStream_t stream) {
  const int* chars      = (const int*)d_in[0];
  const int* chars_mask = (const int*)d_in[1];
  const int* data_mask  = (const int*)d_in[2];
  const void* embed     = d_in[3];
  const void* Wih_fw    = d_in[4];
  const void* Whh_fw    = d_in[5];
  const void* bih_fw    = d_in[6];
  const void* bhh_fw    = d_in[7];
  const void* Wih_bw    = d_in[8];
  const void* Whh_bw    = d_in[9];
  const void* bih_bw    = d_in[10];
  const void* bhh_bw    = d_in[11];
  float* ws = (float*)d_ws;

  // 1) device-side dtype probe (fp32 vs bf16) -> ws[0]
  detect_k<<<1, 64, 0, stream>>>((const u32*)embed, (u32*)ws);

  // 2) canonicalize weights (transpose, widen) + embed/biases into fp32 workspace
  prep_weights<<<2*(IH_F+HH_F)/256, 256, 0, stream>>>(Wih_fw, Whh_fw, Wih_bw, Whh_bw, ws);
  prep_misc<<<MISC_N/256, 256, 0, stream>>>(embed, bih_fw, bhh_fw, bih_bw, bhh_bw, ws);

  // 3) fused embed + input-proj + bidirectional GRU scan + masked concat output
  dim3 grid(NWORDS/MM, 2);
  gru_kernel<<<grid, 256, 0, stream>>>(chars, chars_mask, data_mask, ws, d_out);
}

// Round 3
// 2008.596 us; speedup vs baseline: 1.2206x; 1.2206x over previous
//
#include <hip/hip_runtime.h>
#include <hip/hip_bf16.h>

typedef unsigned int u32;
typedef unsigned short u16;
typedef __attribute__((ext_vector_type(8))) short bf16x8;
typedef __attribute__((ext_vector_type(4))) float f32x4;

// Problem constants
#define NWORDS 4096   // B*S
#define CC 32         // chars per word
#define EE 128        // embed dim
#define HHH 256       // hidden
#define GG 768        // 3*H
#define MMW 32        // words per block
#define VOCABN 262

// Packed-weight workspace layout (u16 units).
// B-fragment pack order: frag[(gt*KC + kc)*64 + lane][j] = W[gt*16 + (lane&15)][kc*32 + (lane>>4)*8 + j]
#define PK_HH (48*8*64*8)                   // 196608 u16 per Whh pack (48 gate-tiles, KC=8)
#define PK_IH (48*4*64*8)                   // 98304 u16  per Wih pack (KC=4)
#define DIR_U16 (2*PK_HH + PK_IH)           // hi, lo, ih  = 491520
#define EMB_OFF_U16 (2*DIR_U16)             // 983040
#define EMB_U16 (VOCABN*EE)                 // 33536
#define BIAS_OFF_U16 (EMB_OFF_U16 + EMB_U16) // 1016576 (byte off 2033152, 4-aligned)
// bias region: per dir 1024 f32: [0..511]=bih+bhh (r,z) ; [512..767]=bih_n ; [768..1023]=bhh_n

__device__ __forceinline__ float bf2f(u16 u){ union{u32 i; float f;} v; v.i=((u32)u)<<16; return v.f; }
__device__ __forceinline__ u16 f2bf(float f){
  __hip_bfloat16 h = __float2bfloat16(f);   // rne
  u16 r; __builtin_memcpy(&r, &h, 2); return r;
}
__device__ __forceinline__ float sigmoid_f(float x){
  float e = __builtin_amdgcn_exp2f(-1.4426950408889634f * x);
  return __builtin_amdgcn_rcpf(1.0f + e);
}
__device__ __forceinline__ float tanh_f(float x){
  float ax = __builtin_fabsf(x);
  float e  = __builtin_amdgcn_exp2f(-2.8853900817779268f * ax);
  float t  = 1.0f - 2.0f * e * __builtin_amdgcn_rcpf(1.0f + e);
  return __builtin_copysignf(t, x);
}

// ---- pack weights into MFMA B-fragment order; Whh split into hi+lo bf16 ----
__global__ void prep_pack(const float* __restrict__ Wih_fw, const float* __restrict__ Whh_fw,
                          const float* __restrict__ Wih_bw, const float* __restrict__ Whh_bw,
                          u16* __restrict__ wsu)
{
  int idx = blockIdx.x*256 + threadIdx.x;       // grid exact: 2*DIR_U16/256 = 3840 blocks
  int d = idx / DIR_U16;
  int r = idx - d*DIR_U16;
  const float* Whh = d ? Whh_bw : Whh_fw;
  const float* Wih = d ? Wih_bw : Wih_fw;
  u16 outv;
  if (r < 2*PK_HH) {
    int e = (r < PK_HH) ? r : (r - PK_HH);
    int j = e & 7, lane = (e >> 3) & 63, kc = (e >> 9) & 7, gt = e >> 12;
    int g = gt*16 + (lane & 15);
    int k = kc*32 + ((lane >> 4) << 3) + j;
    float v = Whh[g*HHH + k];
    u16 hi = f2bf(v);
    outv = (r < PK_HH) ? hi : f2bf(v - bf2f(hi));
  } else {
    int e = r - 2*PK_HH;
    int j = e & 7, lane = (e >> 3) & 63, kc = (e >> 9) & 3, gt = e >> 11;
    int g = gt*16 + (lane & 15);
    int k = kc*32 + ((lane >> 4) << 3) + j;
    outv = f2bf(Wih[g*EE + k]);
  }
  wsu[idx] = outv;
}

// ---- bf16 embed table + fused biases ----
__global__ void prep_misc(const float* __restrict__ emb,
                          const float* __restrict__ bih_fw, const float* __restrict__ bhh_fw,
                          const float* __restrict__ bih_bw, const float* __restrict__ bhh_bw,
                          u16* __restrict__ wsu)
{
  int i = blockIdx.x*256 + threadIdx.x;
  if (i < EMB_U16) { wsu[EMB_OFF_U16 + i] = f2bf(emb[i]); return; }
  int b = i - EMB_U16;
  if (b >= 2048) return;
  int d = b >> 10, o = b & 1023;
  const float* bih = d ? bih_bw : bih_fw;
  const float* bhh = d ? bhh_bw : bhh_fw;
  float v;
  if (o < 512)      v = bih[o] + bhh[o];
  else if (o < 768) v = bih[o - 512 + 512];   // bih_n
  else              v = bhh[o - 768 + 512];   // bhh_n
  ((float*)(wsu + BIAS_OFF_U16))[d*1024 + o] = v;
}

__global__ __launch_bounds__(256, 1)
void gru_mfma(const int* __restrict__ chars, const int* __restrict__ chars_mask,
              const int* __restrict__ data_mask, const u16* __restrict__ wsu,
              float* __restrict__ out)
{
  const int dir   = blockIdx.y;
  const int word0 = blockIdx.x * MMW;
  const int j     = threadIdx.x;
  const int lane  = j & 63, wave = j >> 6;
  const int quad  = lane >> 4, l15 = lane & 15;
  const int w4    = wave * 4, c0 = wave * 64;

  const bf16x8* pHHhi = (const bf16x8*)(wsu + (size_t)dir*DIR_U16);
  const bf16x8* pHHlo = pHHhi + PK_HH/8;
  const bf16x8* pIH   = (const bf16x8*)(wsu + (size_t)dir*DIR_U16 + 2*PK_HH);
  const u16*    embbf = wsu + EMB_OFF_U16;
  const float*  bias  = (const float*)(wsu + BIAS_OFF_U16) + dir*1024;

  // per-wave/lane fragment bases: index add = (s*16+nt)*KC*64 + kc*64 (compile-time under unroll)
  const bf16x8* bHHhi = pHHhi + w4*8*64 + lane;
  const bf16x8* bHHlo = pHHlo + w4*8*64 + lane;
  const bf16x8* bIH   = pIH   + w4*4*64 + lane;

  __shared__ __align__(16) float sh_hf[MMW][HHH+1];   // fp32 h           (~32.9 KB)
  __shared__ __align__(16) u16   sh_hhi[MMW][264];    // bf16 hi, A-layout (16.9 KB)
  __shared__ __align__(16) u16   sh_hlo[MMW][264];    // bf16 lo           (16.9 KB)
  __shared__ __align__(16) u16   sh_x[MMW][136];      // x_t bf16          (8.7 KB)
  __shared__ float sh_m[MMW];

  // zero h state
  for (int i = j; i < MMW*(HHH+1); i += 256) ((float*)sh_hf)[i] = 0.0f;
  for (int i = j; i < MMW*264; i += 256) { ((u16*)sh_hhi)[i] = 0; ((u16*)sh_hlo)[i] = 0; }

  // per-lane biases (4 gate kinds x 4 n-tiles)
  float bR[4], bZ[4], bXN[4], bHN[4];
  #pragma unroll
  for (int nt = 0; nt < 4; ++nt) {
    int c = c0 + nt*16 + l15;
    bR[nt]  = bias[c];        bZ[nt]  = bias[256 + c];
    bXN[nt] = bias[512 + c];  bHN[nt] = bias[768 + c];
  }

  const int sw = j >> 3, sp = j & 7;   // x-staging: word, 16-element part

  #pragma unroll 1
  for (int s = 0; s < CC; ++s) {
    const int t = dir ? (CC - 1 - s) : s;
    __syncthreads();                                   // S0: prev h writes visible, prev x reads done
    {
      int ci = chars[(word0 + sw)*CC + t];
      const uint4* er = (const uint4*)(embbf + (size_t)ci*EE);
      uint4 a0 = er[sp*2], a1 = er[sp*2 + 1];
      *(uint4*)&sh_x[sw][sp*16]     = a0;
      *(uint4*)&sh_x[sw][sp*16 + 8] = a1;
      if (j < MMW) sh_m[j] = (float)chars_mask[(word0 + j)*CC + t];
    }
    __syncthreads();                                   // S1: x/mask staged

    // acc[0]=r, acc[1]=z, acc[2]=xn, acc[3]=hn ; [m-tile][n-tile]
    f32x4 acc[4][2][4];
    #pragma unroll
    for (int m = 0; m < 2; ++m)
      #pragma unroll
      for (int nt = 0; nt < 4; ++nt) {
        acc[0][m][nt] = (f32x4){bR[nt], bR[nt], bR[nt], bR[nt]};
        acc[1][m][nt] = (f32x4){bZ[nt], bZ[nt], bZ[nt], bZ[nt]};
        acc[2][m][nt] = (f32x4){bXN[nt], bXN[nt], bXN[nt], bXN[nt]};
        acc[3][m][nt] = (f32x4){bHN[nt], bHN[nt], bHN[nt], bHN[nt]};
      }

    // ---- input projection: x(bf16) @ Wih^T, K=128 ----
    #pragma unroll
    for (int kc = 0; kc < 4; ++kc) {
      bf16x8 ax0 = *(const bf16x8*)&sh_x[l15][kc*32 + quad*8];
      bf16x8 ax1 = *(const bf16x8*)&sh_x[16 + l15][kc*32 + quad*8];
      #pragma unroll
      for (int g = 0; g < 3; ++g)
        #pragma unroll
        for (int nt = 0; nt < 4; ++nt) {
          bf16x8 b = bIH[((g*16 + nt)*4 + kc)*64];
          acc[g][0][nt] = __builtin_amdgcn_mfma_f32_16x16x32_bf16(ax0, b, acc[g][0][nt], 0,0,0);
          acc[g][1][nt] = __builtin_amdgcn_mfma_f32_16x16x32_bf16(ax1, b, acc[g][1][nt], 0,0,0);
        }
    }

    // ---- recurrence: (hhi+hlo) @ (Whi+Wlo)^T, K=256, 3-product split ----
    #pragma unroll
    for (int kc = 0; kc < 8; ++kc) {
      bf16x8 ah0 = *(const bf16x8*)&sh_hhi[l15][kc*32 + quad*8];
      bf16x8 ah1 = *(const bf16x8*)&sh_hhi[16 + l15][kc*32 + quad*8];
      bf16x8 al0 = *(const bf16x8*)&sh_hlo[l15][kc*32 + quad*8];
      bf16x8 al1 = *(const bf16x8*)&sh_hlo[16 + l15][kc*32 + quad*8];
      #pragma unroll
      for (int g = 0; g < 3; ++g)
        #pragma unroll
        for (int nt = 0; nt < 4; ++nt) {
          const int ai = (g < 2) ? g : 3;             // n-gate recurrence -> hn accumulator
          bf16x8 bhi = bHHhi[((g*16 + nt)*8 + kc)*64];
          bf16x8 blo = bHHlo[((g*16 + nt)*8 + kc)*64];
          acc[ai][0][nt] = __builtin_amdgcn_mfma_f32_16x16x32_bf16(ah0, bhi, acc[ai][0][nt], 0,0,0);
          acc[ai][1][nt] = __builtin_amdgcn_mfma_f32_16x16x32_bf16(ah1, bhi, acc[ai][1][nt], 0,0,0);
          acc[ai][0][nt] = __builtin_amdgcn_mfma_f32_16x16x32_bf16(al0, bhi, acc[ai][0][nt], 0,0,0);
          acc[ai][1][nt] = __builtin_amdgcn_mfma_f32_16x16x32_bf16(al1, bhi, acc[ai][1][nt], 0,0,0);
          acc[ai][0][nt] = __builtin_amdgcn_mfma_f32_16x16x32_bf16(ah0, blo, acc[ai][0][nt], 0,0,0);
          acc[ai][1][nt] = __builtin_amdgcn_mfma_f32_16x16x32_bf16(ah1, blo, acc[ai][1][nt], 0,0,0);
        }
    }

    __syncthreads();                                   // S2: all h/x fragment reads done

    // ---- gate math + h update (each lane owns its (word,ch) pairs) ----
    #pragma unroll
    for (int m = 0; m < 2; ++m)
      #pragma unroll
      for (int nt = 0; nt < 4; ++nt) {
        const int ch = c0 + nt*16 + l15;
        #pragma unroll
        for (int r = 0; r < 4; ++r) {
          const int word = m*16 + quad*4 + r;
          float rr = sigmoid_f(acc[0][m][nt][r]);
          float zz = sigmoid_f(acc[1][m][nt][r]);
          float nn = tanh_f(fmaf(rr, acc[3][m][nt][r], acc[2][m][nt][r]));
          float hold = sh_hf[word][ch];
          float hnew = fmaf(zz, hold - nn, nn);                // (1-z)*n + z*h
          float hm   = fmaf(sh_m[word], hnew - hold, hold);    // mask freeze
          sh_hf[word][ch] = hm;
          u16 hi = f2bf(hm);
          sh_hhi[word][ch] = hi;
          sh_hlo[word][ch] = f2bf(hm - bf2f(hi));
        }
      }
  }
  __syncthreads();

  #pragma unroll 1
  for (int w = 0; w < MMW; ++w) {
    float dm = (float)data_mask[word0 + w];
    out[(size_t)(word0 + w)*(2*HHH) + dir*HHH + j] = sh_hf[w][j] * dm;
  }
}

extern "C" void kernel_launch(void* const* d_in, const int* in_sizes, int n_in,
                              void* d_out, int out_size, void* d_ws, size_t ws_size,
                              hipStream_t stream) {
  const int*   chars      = (const int*)d_in[0];
  const int*   chars_mask = (const int*)d_in[1];
  const int*   data_mask  = (const int*)d_in[2];
  const float* embed      = (const float*)d_in[3];
  const float* Wih_fw     = (const float*)d_in[4];
  const float* Whh_fw     = (const float*)d_in[5];
  const float* bih_fw     = (const float*)d_in[6];
  const float* bhh_fw     = (const float*)d_in[7];
  const float* Wih_bw     = (const float*)d_in[8];
  const float* Whh_bw     = (const float*)d_in[9];
  const float* bih_bw     = (const float*)d_in[10];
  const float* bhh_bw     = (const float*)d_in[11];
  u16* wsu = (u16*)d_ws;

  prep_pack<<<2*DIR_U16/256, 256, 0, stream>>>(Wih_fw, Whh_fw, Wih_bw, Whh_bw, wsu);
  prep_misc<<<(EMB_U16 + 2048 + 255)/256, 256, 0, stream>>>(embed, bih_fw, bhh_fw, bih_bw, bhh_bw, wsu);

  dim3 grid(NWORDS/MMW, 2);
  gru_mfma<<<grid, 256, 0, stream>>>(chars, chars_mask, data_mask, wsu, (float*)d_out);
}

// Round 4
// 1414.943 us; speedup vs baseline: 1.7327x; 1.4196x over previous
//
#include <hip/hip_runtime.h>
#include <hip/hip_bf16.h>

typedef unsigned int u32;
typedef unsigned short u16;
typedef __attribute__((ext_vector_type(8))) short bf16x8;
typedef __attribute__((ext_vector_type(4))) float f32x4;

// Problem constants
#define NWORDS 4096   // B*S
#define CC 32         // chars per word
#define EE 128        // embed dim
#define HHH 256       // hidden
#define MMW 32        // words per block
#define VOCABN 262

// Packed-weight workspace layout (u16 units), per direction:
//   HH: frag[(nt*3+g)*8+kc][p(hi/lo)][lane][8]  -> 16*3*8*2*512 = 393216 u16
//   IH: frag[(nt*3+g)*4+kc][lane][8]            -> 16*3*4*512   =  98304 u16
// frag content (B-operand): W[g*256 + nt*16 + (lane&15)][kc*32 + (lane>>4)*8 + j]
#define PK_HHD (16*3*8*2*512)               // 393216
#define PK_IHD (16*3*4*512)                 // 98304
#define DIR_U16 (PK_HHD + PK_IHD)           // 491520
#define EMB_OFF_U16 (2*DIR_U16)             // 983040
#define EMB_U16 (VOCABN*EE)                 // 33536
#define BIAS_OFF_U16 (EMB_OFF_U16 + EMB_U16) // 1016576 (byte 2033152, 4-aligned)
// bias region: per dir 1024 f32: [0..511]=bih+bhh (r,z) ; [512..767]=bih_n ; [768..1023]=bhh_n

__device__ __forceinline__ float bf2f(u16 u){ union{u32 i; float f;} v; v.i=((u32)u)<<16; return v.f; }
__device__ __forceinline__ u16 f2bf(float f){
  __hip_bfloat16 h = __float2bfloat16(f);   // rne
  u16 r; __builtin_memcpy(&r, &h, 2); return r;
}
__device__ __forceinline__ float sigmoid_f(float x){
  float e = __builtin_amdgcn_exp2f(-1.4426950408889634f * x);
  return __builtin_amdgcn_rcpf(1.0f + e);
}
__device__ __forceinline__ float tanh_f(float x){
  float ax = __builtin_fabsf(x);
  float e  = __builtin_amdgcn_exp2f(-2.8853900817779268f * ax);
  float t  = 1.0f - 2.0f * e * __builtin_amdgcn_rcpf(1.0f + e);
  return __builtin_copysignf(t, x);
}

// ---- pack weights into per-wave MFMA B-fragment order; Whh split hi+lo ----
__global__ void prep_pack(const float* __restrict__ Wih_fw, const float* __restrict__ Whh_fw,
                          const float* __restrict__ Wih_bw, const float* __restrict__ Whh_bw,
                          u16* __restrict__ wsu)
{
  int idx = blockIdx.x*256 + threadIdx.x;       // grid exact: 2*DIR_U16/256 = 3840 blocks
  int d = idx / DIR_U16;
  int r = idx - d*DIR_U16;
  const float* Whh = d ? Whh_bw : Whh_fw;
  const float* Wih = d ? Wih_bw : Wih_fw;
  u16 outv;
  if (r < PK_HHD) {
    int e = r;
    int jj  = e & 7;
    int lane = (e >> 3) & 63;
    int p   = (e >> 9) & 1;
    int kc  = (e >> 10) & 7;
    int gnt = e >> 13;                 // nt*3+g, < 48
    int g = gnt % 3, nt = gnt / 3;
    int row = g*256 + nt*16 + (lane & 15);
    int k   = kc*32 + ((lane >> 4) << 3) + jj;
    float v = Whh[row*HHH + k];
    u16 hi = f2bf(v);
    outv = p ? f2bf(v - bf2f(hi)) : hi;
  } else {
    int e = r - PK_HHD;
    int jj  = e & 7;
    int lane = (e >> 3) & 63;
    int kc  = (e >> 9) & 3;
    int gnt = e >> 11;                 // < 48
    int g = gnt % 3, nt = gnt / 3;
    int row = g*256 + nt*16 + (lane & 15);
    int k   = kc*32 + ((lane >> 4) << 3) + jj;
    outv = f2bf(Wih[row*EE + k]);
  }
  wsu[idx] = outv;
}

// ---- bf16 embed table + fused biases ----
__global__ void prep_misc(const float* __restrict__ emb,
                          const float* __restrict__ bih_fw, const float* __restrict__ bhh_fw,
                          const float* __restrict__ bih_bw, const float* __restrict__ bhh_bw,
                          u16* __restrict__ wsu)
{
  int i = blockIdx.x*256 + threadIdx.x;
  if (i < EMB_U16) { wsu[EMB_OFF_U16 + i] = f2bf(emb[i]); return; }
  int b = i - EMB_U16;
  if (b >= 2048) return;
  int d = b >> 10, o = b & 1023;
  const float* bih = d ? bih_bw : bih_fw;
  const float* bhh = d ? bhh_bw : bhh_fw;
  float v;
  if (o < 512)      v = bih[o] + bhh[o];
  else if (o < 768) v = bih[o - 512 + 512];   // bih_n
  else              v = bhh[o - 768 + 512];   // bhh_n
  ((float*)(wsu + BIAS_OFF_U16))[d*1024 + o] = v;
}

__global__ __launch_bounds__(1024)
void gru_mfma(const int* __restrict__ chars, const int* __restrict__ chars_mask,
              const int* __restrict__ data_mask, const u16* __restrict__ wsu,
              float* __restrict__ out)
{
  const int dir   = blockIdx.y;
  const int word0 = blockIdx.x * MMW;
  const int j     = threadIdx.x;            // 0..1023 = 16 waves
  const int wave  = j >> 6, lane = j & 63;
  const int quad  = lane >> 4, l15 = lane & 15;

  const u16* wbase = wsu + (size_t)dir*DIR_U16;
  const bf16x8* pHH = (const bf16x8*)wbase;             // [(nt*3+g)*8+kc][p][64]
  const bf16x8* pIH = (const bf16x8*)(wbase + PK_HHD);  // [(nt*3+g)*4+kc][64]
  const u16*    embbf = wsu + EMB_OFF_U16;
  const float*  bias  = (const float*)(wsu + BIAS_OFF_U16) + dir*1024;

  // per-wave/lane fragment bases (this wave's gate-tile nt == wave)
  const bf16x8* bHH = pHH + (size_t)(wave*3)*8*2*64 + lane;
  const bf16x8* bIH = pIH + (size_t)(wave*3)*4*64 + lane;

  __shared__ __align__(16) u16   sh_hhi[MMW][264];    // bf16 hi of h, A-layout (16.9 KB)
  __shared__ __align__(16) u16   sh_hlo[MMW][264];    // bf16 lo of h          (16.9 KB)
  __shared__ __align__(16) u16   sh_x[MMW][136];      // x_t bf16              (8.7 KB)
  __shared__ float sh_m[MMW];

  for (int i = j; i < MMW*264; i += 1024) { (&sh_hhi[0][0])[i] = 0; (&sh_hlo[0][0])[i] = 0; }

  const int ch = wave*16 + l15;             // this lane's output channel
  const float bR  = bias[ch],        bZ  = bias[256 + ch];
  const float bXN = bias[512 + ch],  bHN = bias[768 + ch];

  const int sw = j >> 5, sp = j & 31;       // x-staging: word, 4-half part

  #pragma unroll 1
  for (int s = 0; s < CC; ++s) {
    const int t = dir ? (CC - 1 - s) : s;
    __syncthreads();                                   // S0: h writes visible, prev x reads done
    {
      int ci = chars[(word0 + sw)*CC + t];
      *(uint2*)&sh_x[sw][sp*4] = *(const uint2*)(embbf + (size_t)ci*EE + sp*4);
      if (j < MMW) sh_m[j] = (float)chars_mask[(word0 + j)*CC + t];
    }
    __syncthreads();                                   // S1: x/mask staged

    // acc[0]=r, acc[1]=z, acc[2]=xn, acc[3]=hn ; [m-tile]
    f32x4 acc[4][2];
    acc[0][0] = (f32x4){bR,bR,bR,bR};   acc[0][1] = acc[0][0];
    acc[1][0] = (f32x4){bZ,bZ,bZ,bZ};   acc[1][1] = acc[1][0];
    acc[2][0] = (f32x4){bXN,bXN,bXN,bXN}; acc[2][1] = acc[2][0];
    acc[3][0] = (f32x4){bHN,bHN,bHN,bHN}; acc[3][1] = acc[3][0];

    // ---- input projection: x(bf16) @ Wih^T, K=128 ----
    #pragma unroll
    for (int kc = 0; kc < 4; ++kc) {
      bf16x8 ax0 = *(const bf16x8*)&sh_x[l15][kc*32 + quad*8];
      bf16x8 ax1 = *(const bf16x8*)&sh_x[16 + l15][kc*32 + quad*8];
      #pragma unroll
      for (int g = 0; g < 3; ++g) {
        bf16x8 b = bIH[(g*4 + kc)*64];
        const int ai = (g < 2) ? g : 2;
        acc[ai][0] = __builtin_amdgcn_mfma_f32_16x16x32_bf16(ax0, b, acc[ai][0], 0,0,0);
        acc[ai][1] = __builtin_amdgcn_mfma_f32_16x16x32_bf16(ax1, b, acc[ai][1], 0,0,0);
      }
    }

    // ---- recurrence: (hhi+hlo) @ (Whi+Wlo)^T, K=256, 3-product split ----
    #pragma unroll
    for (int kc = 0; kc < 8; ++kc) {
      bf16x8 ah0 = *(const bf16x8*)&sh_hhi[l15][kc*32 + quad*8];
      bf16x8 ah1 = *(const bf16x8*)&sh_hhi[16 + l15][kc*32 + quad*8];
      bf16x8 al0 = *(const bf16x8*)&sh_hlo[l15][kc*32 + quad*8];
      bf16x8 al1 = *(const bf16x8*)&sh_hlo[16 + l15][kc*32 + quad*8];
      #pragma unroll
      for (int g = 0; g < 3; ++g) {
        bf16x8 bhi = bHH[((g*8 + kc)*2 + 0)*64];
        bf16x8 blo = bHH[((g*8 + kc)*2 + 1)*64];
        const int ai = (g < 2) ? g : 3;
        acc[ai][0] = __builtin_amdgcn_mfma_f32_16x16x32_bf16(ah0, bhi, acc[ai][0], 0,0,0);
        acc[ai][1] = __builtin_amdgcn_mfma_f32_16x16x32_bf16(ah1, bhi, acc[ai][1], 0,0,0);
        acc[ai][0] = __builtin_amdgcn_mfma_f32_16x16x32_bf16(al0, bhi, acc[ai][0], 0,0,0);
        acc[ai][1] = __builtin_amdgcn_mfma_f32_16x16x32_bf16(al1, bhi, acc[ai][1], 0,0,0);
        acc[ai][0] = __builtin_amdgcn_mfma_f32_16x16x32_bf16(ah0, blo, acc[ai][0], 0,0,0);
        acc[ai][1] = __builtin_amdgcn_mfma_f32_16x16x32_bf16(ah1, blo, acc[ai][1], 0,0,0);
      }
    }

    __syncthreads();                                   // S2: all h/x fragment reads done

    // ---- gate math + h update (lane owns (word, ch) pairs) ----
    #pragma unroll
    for (int m = 0; m < 2; ++m)
      #pragma unroll
      for (int r = 0; r < 4; ++r) {
        const int word = m*16 + quad*4 + r;
        float rr = sigmoid_f(acc[0][m][r]);
        float zz = sigmoid_f(acc[1][m][r]);
        float nn = tanh_f(fmaf(rr, acc[3][m][r], acc[2][m][r]));
        float hold = bf2f(sh_hhi[word][ch]) + bf2f(sh_hlo[word][ch]);
        float hnew = fmaf(zz, hold - nn, nn);              // (1-z)*n + z*h
        float hm   = fmaf(sh_m[word], hnew - hold, hold);  // mask freeze
        u16 hi = f2bf(hm);
        sh_hhi[word][ch] = hi;
        sh_hlo[word][ch] = f2bf(hm - bf2f(hi));
      }
  }
  __syncthreads();

  // ---- output: 32 words x 256 ch, 8 per thread, coalesced fp32 ----
  const int oc = j & 255, og = j >> 8;     // 4 groups of 8 words
  #pragma unroll
  for (int i = 0; i < 8; ++i) {
    const int w = og*8 + i;
    float dm = (float)data_mask[word0 + w];
    float h = bf2f(sh_hhi[w][oc]) + bf2f(sh_hlo[w][oc]);
    out[(size_t)(word0 + w)*(2*HHH) + dir*HHH + oc] = h * dm;
  }
}

extern "C" void kernel_launch(void* const* d_in, const int* in_sizes, int n_in,
                              void* d_out, int out_size, void* d_ws, size_t ws_size,
                              hipStream_t stream) {
  const int*   chars      = (const int*)d_in[0];
  const int*   chars_mask = (const int*)d_in[1];
  const int*   data_mask  = (const int*)d_in[2];
  const float* embed      = (const float*)d_in[3];
  const float* Wih_fw     = (const float*)d_in[4];
  const float* Whh_fw     = (const float*)d_in[5];
  const float* bih_fw     = (const float*)d_in[6];
  const float* bhh_fw     = (const float*)d_in[7];
  const float* Wih_bw     = (const float*)d_in[8];
  const float* Whh_bw     = (const float*)d_in[9];
  const float* bih_bw     = (const float*)d_in[10];
  const float* bhh_bw     = (const float*)d_in[11];
  u16* wsu = (u16*)d_ws;

  prep_pack<<<2*DIR_U16/256, 256, 0, stream>>>(Wih_fw, Whh_fw, Wih_bw, Whh_bw, wsu);
  prep_misc<<<(EMB_U16 + 2048 + 255)/256, 256, 0, stream>>>(embed, bih_fw, bhh_fw, bih_bw, bhh_bw, wsu);

  dim3 grid(NWORDS/MMW, 2);
  gru_mfma<<<grid, 1024, 0, stream>>>(chars, chars_mask, data_mask, wsu, (float*)d_out);
}

// Round 5
// 1181.052 us; speedup vs baseline: 2.0758x; 1.1980x over previous
//
#include <hip/hip_runtime.h>
#include <hip/hip_bf16.h>

typedef unsigned int u32;
typedef unsigned short u16;
typedef __attribute__((ext_vector_type(8))) short bf16x8;
typedef __attribute__((ext_vector_type(4))) float f32x4;

// Problem constants
#define NWORDS 4096   // B*S
#define CC 32         // chars per word
#define EE 128        // embed dim
#define HHH 256       // hidden
#define MMW 64        // words per block (4 m-tiles per wave)
#define VOCABN 262

// Packed-weight workspace layout (u16 units), per direction:
//   HH: frag[(nt*3+g)*8+kc][p(hi/lo)][lane][8]  -> 16*3*8*2*512 = 393216 u16
//   IH: frag[(nt*3+g)*4+kc][lane][8]            -> 16*3*4*512   =  98304 u16
// frag content (B-operand): W[g*256 + nt*16 + (lane&15)][kc*32 + (lane>>4)*8 + j]
#define PK_HHD (16*3*8*2*512)               // 393216
#define PK_IHD (16*3*4*512)                 // 98304
#define DIR_U16 (PK_HHD + PK_IHD)           // 491520
#define EMB_OFF_U16 (2*DIR_U16)             // 983040
#define EMB_U16 (VOCABN*EE)                 // 33536
#define BIAS_OFF_U16 (EMB_OFF_U16 + EMB_U16) // 1016576 (byte 2033152, 4-aligned)
// bias region: per dir 1024 f32: [0..511]=bih+bhh (r,z) ; [512..767]=bih_n ; [768..1023]=bhh_n

__device__ __forceinline__ float bf2f(u16 u){ union{u32 i; float f;} v; v.i=((u32)u)<<16; return v.f; }
__device__ __forceinline__ u16 f2bf(float f){
  __hip_bfloat16 h = __float2bfloat16(f);   // rne
  u16 r; __builtin_memcpy(&r, &h, 2); return r;
}
__device__ __forceinline__ float sigmoid_f(float x){
  float e = __builtin_amdgcn_exp2f(-1.4426950408889634f * x);
  return __builtin_amdgcn_rcpf(1.0f + e);
}
__device__ __forceinline__ float tanh_f(float x){
  float ax = __builtin_fabsf(x);
  float e  = __builtin_amdgcn_exp2f(-2.8853900817779268f * ax);
  float t  = 1.0f - 2.0f * e * __builtin_amdgcn_rcpf(1.0f + e);
  return __builtin_copysignf(t, x);
}

// ---- pack weights into per-wave MFMA B-fragment order; Whh split hi+lo ----
__global__ void prep_pack(const float* __restrict__ Wih_fw, const float* __restrict__ Whh_fw,
                          const float* __restrict__ Wih_bw, const float* __restrict__ Whh_bw,
                          u16* __restrict__ wsu)
{
  int idx = blockIdx.x*256 + threadIdx.x;       // grid exact: 2*DIR_U16/256 = 3840 blocks
  int d = idx / DIR_U16;
  int r = idx - d*DIR_U16;
  const float* Whh = d ? Whh_bw : Whh_fw;
  const float* Wih = d ? Wih_bw : Wih_fw;
  u16 outv;
  if (r < PK_HHD) {
    int e = r;
    int jj  = e & 7;
    int lane = (e >> 3) & 63;
    int p   = (e >> 9) & 1;
    int kc  = (e >> 10) & 7;
    int gnt = e >> 13;                 // nt*3+g, < 48
    int g = gnt % 3, nt = gnt / 3;
    int row = g*256 + nt*16 + (lane & 15);
    int k   = kc*32 + ((lane >> 4) << 3) + jj;
    float v = Whh[row*HHH + k];
    u16 hi = f2bf(v);
    outv = p ? f2bf(v - bf2f(hi)) : hi;
  } else {
    int e = r - PK_HHD;
    int jj  = e & 7;
    int lane = (e >> 3) & 63;
    int kc  = (e >> 9) & 3;
    int gnt = e >> 11;                 // < 48
    int g = gnt % 3, nt = gnt / 3;
    int row = g*256 + nt*16 + (lane & 15);
    int k   = kc*32 + ((lane >> 4) << 3) + jj;
    outv = f2bf(Wih[row*EE + k]);
  }
  wsu[idx] = outv;
}

// ---- bf16 embed table + fused biases ----
__global__ void prep_misc(const float* __restrict__ emb,
                          const float* __restrict__ bih_fw, const float* __restrict__ bhh_fw,
                          const float* __restrict__ bih_bw, const float* __restrict__ bhh_bw,
                          u16* __restrict__ wsu)
{
  int i = blockIdx.x*256 + threadIdx.x;
  if (i < EMB_U16) { wsu[EMB_OFF_U16 + i] = f2bf(emb[i]); return; }
  int b = i - EMB_U16;
  if (b >= 2048) return;
  int d = b >> 10, o = b & 1023;
  const float* bih = d ? bih_bw : bih_fw;
  const float* bhh = d ? bhh_bw : bhh_fw;
  float v;
  if (o < 512)      v = bih[o] + bhh[o];
  else if (o < 768) v = bih[o - 512 + 512];   // bih_n
  else              v = bhh[o - 768 + 512];   // bhh_n
  ((float*)(wsu + BIAS_OFF_U16))[d*1024 + o] = v;
}

__global__ __launch_bounds__(1024)
void gru_mfma(const int* __restrict__ chars, const int* __restrict__ chars_mask,
              const int* __restrict__ data_mask, const u16* __restrict__ wsu,
              float* __restrict__ out)
{
  // dir = blockIdx&1: with round-robin block->XCD (%8), every block on an XCD
  // shares one direction -> per-XCD weight working set ~1 MB (L2-resident).
  const int dir   = blockIdx.x & 1;
  const int word0 = (blockIdx.x >> 1) * MMW;
  const int j     = threadIdx.x;            // 0..1023 = 16 waves
  const int wave  = j >> 6, lane = j & 63;
  const int quad  = lane >> 4, l15 = lane & 15;

  const u16* wbase = wsu + (size_t)dir*DIR_U16;
  const bf16x8* pHH = (const bf16x8*)wbase;             // [(nt*3+g)*8+kc][p][64]
  const bf16x8* pIH = (const bf16x8*)(wbase + PK_HHD);  // [(nt*3+g)*4+kc][64]
  const u16*    embbf = wsu + EMB_OFF_U16;
  const float*  bias  = (const float*)(wsu + BIAS_OFF_U16) + dir*1024;

  // per-wave/lane fragment bases (this wave's gate-tile nt == wave)
  const bf16x8* bHH = pHH + (size_t)(wave*3)*8*2*64 + lane;
  const bf16x8* bIH = pIH + (size_t)(wave*3)*4*64 + lane;

  __shared__ __align__(16) u16   sh_hhi[MMW][264];    // bf16 hi of h, A-layout (33.8 KB)
  __shared__ __align__(16) u16   sh_hlo[MMW][264];    // bf16 lo of h          (33.8 KB)
  __shared__ __align__(16) u16   sh_x[MMW][136];      // x_t bf16              (17.4 KB)
  __shared__ float sh_m[MMW];

  for (int i = j; i < MMW*264; i += 1024) { (&sh_hhi[0][0])[i] = 0; (&sh_hlo[0][0])[i] = 0; }

  const int ch = wave*16 + l15;             // this lane's output channel
  const float bR  = bias[ch],        bZ  = bias[256 + ch];
  const float bXN = bias[512 + ch],  bHN = bias[768 + ch];

  const int sw = j >> 4, sp = j & 15;       // x-staging: word, 8-u16 part

  #pragma unroll 1
  for (int s = 0; s < CC; ++s) {
    const int t = dir ? (CC - 1 - s) : s;
    __syncthreads();                                   // S0: h writes visible, prev x reads done
    {
      int ci = chars[(word0 + sw)*CC + t];
      *(uint4*)&sh_x[sw][sp*8] = *(const uint4*)(embbf + (size_t)ci*EE + sp*8);
      if (j < MMW) sh_m[j] = (float)chars_mask[(word0 + j)*CC + t];
    }
    __syncthreads();                                   // S1: x/mask staged

    // acc[0]=r, acc[1]=z, acc[2]=xn, acc[3]=hn ; [m-tile 0..3]
    f32x4 acc[4][4];
    #pragma unroll
    for (int m = 0; m < 4; ++m) {
      acc[0][m] = (f32x4){bR,bR,bR,bR};
      acc[1][m] = (f32x4){bZ,bZ,bZ,bZ};
      acc[2][m] = (f32x4){bXN,bXN,bXN,bXN};
      acc[3][m] = (f32x4){bHN,bHN,bHN,bHN};
    }

    // ---- input projection: x(bf16) @ Wih^T, K=128 ----
    #pragma unroll
    for (int kc = 0; kc < 4; ++kc) {
      bf16x8 ax[4];
      #pragma unroll
      for (int m = 0; m < 4; ++m)
        ax[m] = *(const bf16x8*)&sh_x[m*16 + l15][kc*32 + quad*8];
      #pragma unroll
      for (int g = 0; g < 3; ++g) {
        bf16x8 b = bIH[(g*4 + kc)*64];
        const int ai = (g < 2) ? g : 2;
        #pragma unroll
        for (int m = 0; m < 4; ++m)
          acc[ai][m] = __builtin_amdgcn_mfma_f32_16x16x32_bf16(ax[m], b, acc[ai][m], 0,0,0);
      }
    }

    // ---- recurrence: (hhi+hlo) @ (Whi+Wlo)^T, K=256, 3-product split ----
    #pragma unroll
    for (int kc = 0; kc < 8; ++kc) {
      bf16x8 ah[4], al[4];
      #pragma unroll
      for (int m = 0; m < 4; ++m) {
        ah[m] = *(const bf16x8*)&sh_hhi[m*16 + l15][kc*32 + quad*8];
        al[m] = *(const bf16x8*)&sh_hlo[m*16 + l15][kc*32 + quad*8];
      }
      #pragma unroll
      for (int g = 0; g < 3; ++g) {
        bf16x8 bhi = bHH[((g*8 + kc)*2 + 0)*64];
        bf16x8 blo = bHH[((g*8 + kc)*2 + 1)*64];
        const int ai = (g < 2) ? g : 3;
        #pragma unroll
        for (int m = 0; m < 4; ++m) {
          acc[ai][m] = __builtin_amdgcn_mfma_f32_16x16x32_bf16(ah[m], bhi, acc[ai][m], 0,0,0);
          acc[ai][m] = __builtin_amdgcn_mfma_f32_16x16x32_bf16(al[m], bhi, acc[ai][m], 0,0,0);
          acc[ai][m] = __builtin_amdgcn_mfma_f32_16x16x32_bf16(ah[m], blo, acc[ai][m], 0,0,0);
        }
      }
    }

    __syncthreads();                                   // S2: all h/x fragment reads done

    // ---- gate math + h update (lane owns (word, ch) pairs) ----
    #pragma unroll
    for (int m = 0; m < 4; ++m)
      #pragma unroll
      for (int r = 0; r < 4; ++r) {
        const int word = m*16 + quad*4 + r;
        float rr = sigmoid_f(acc[0][m][r]);
        float zz = sigmoid_f(acc[1][m][r]);
        float nn = tanh_f(fmaf(rr, acc[3][m][r], acc[2][m][r]));
        float hold = bf2f(sh_hhi[word][ch]) + bf2f(sh_hlo[word][ch]);
        float hnew = fmaf(zz, hold - nn, nn);              // (1-z)*n + z*h
        float hm   = fmaf(sh_m[word], hnew - hold, hold);  // mask freeze
        u16 hi = f2bf(hm);
        sh_hhi[word][ch] = hi;
        sh_hlo[word][ch] = f2bf(hm - bf2f(hi));
      }
  }
  __syncthreads();

  // ---- output: 64 words x 256 ch, 16 per thread, coalesced fp32 ----
  const int oc = j & 255, og = j >> 8;     // 4 groups of 16 words
  #pragma unroll
  for (int i = 0; i < 16; ++i) {
    const int w = og*16 + i;
    float dm = (float)data_mask[word0 + w];
    float h = bf2f(sh_hhi[w][oc]) + bf2f(sh_hlo[w][oc]);
    out[(size_t)(word0 + w)*(2*HHH) + dir*HHH + oc] = h * dm;
  }
}

extern "C" void kernel_launch(void* const* d_in, const int* in_sizes, int n_in,
                              void* d_out, int out_size, void* d_ws, size_t ws_size,
                              hipStream_t stream) {
  const int*   chars      = (const int*)d_in[0];
  const int*   chars_mask = (const int*)d_in[1];
  const int*   data_mask  = (const int*)d_in[2];
  const float* embed      = (const float*)d_in[3];
  const float* Wih_fw     = (const float*)d_in[4];
  const float* Whh_fw     = (const float*)d_in[5];
  const float* bih_fw     = (const float*)d_in[6];
  const float* bhh_fw     = (const float*)d_in[7];
  const float* Wih_bw     = (const float*)d_in[8];
  const float* Whh_bw     = (const float*)d_in[9];
  const float* bih_bw     = (const float*)d_in[10];
  const float* bhh_bw     = (const float*)d_in[11];
  u16* wsu = (u16*)d_ws;

  prep_pack<<<2*DIR_U16/256, 256, 0, stream>>>(Wih_fw, Whh_fw, Wih_bw, Whh_bw, wsu);
  prep_misc<<<(EMB_U16 + 2048 + 255)/256, 256, 0, stream>>>(embed, bih_fw, bhh_fw, bih_bw, bhh_bw, wsu);

  // 128 blocks: (word-group, dir) packed so dir == blockIdx&1
  gru_mfma<<<(NWORDS/MMW)*2, 1024, 0, stream>>>(chars, chars_mask, data_mask, wsu, (float*)d_out);
}

// Round 6
// 814.328 us; speedup vs baseline: 3.0107x; 1.4503x over previous
//
#include <hip/hip_runtime.h>
#include <hip/hip_bf16.h>

typedef unsigned int u32;
typedef unsigned short u16;
typedef __attribute__((ext_vector_type(8))) short bf16x8;
typedef __attribute__((ext_vector_type(4))) float f32x4;

// Problem constants
#define NWORDS 4096   // B*S
#define CC 32         // chars per word
#define EE 128        // embed dim
#define HHH 256       // hidden
#define MMW 64        // words per block (4 m-tiles per wave)
#define VOCABN 262

// Packed-weight workspace layout (u16 units), per direction:
//   HH: frag[(nt*3+g)*8+kc][lane][8]  -> 16*3*8*512 = 196608 u16   (bf16-hi only)
//   IH: frag[(nt*3+g)*4+kc][lane][8]  -> 16*3*4*512 =  98304 u16
// frag content (B-operand): W[g*256 + nt*16 + (lane&15)][kc*32 + (lane>>4)*8 + j]
#define PK_HHD (16*3*8*512)                 // 196608
#define PK_IHD (16*3*4*512)                 // 98304
#define DIR_U16 (PK_HHD + PK_IHD)           // 294912
#define EMB_OFF_U16 (2*DIR_U16)             // 589824
#define EMB_U16 (VOCABN*EE)                 // 33536
#define BIAS_OFF_U16 (EMB_OFF_U16 + EMB_U16) // 623360 (byte 1246720, 4-aligned)
// bias region: per dir 1024 f32: [0..511]=bih+bhh (r,z) ; [512..767]=bih_n ; [768..1023]=bhh_n

__device__ __forceinline__ float bf2f(u16 u){ union{u32 i; float f;} v; v.i=((u32)u)<<16; return v.f; }
__device__ __forceinline__ u16 f2bf(float f){
  __hip_bfloat16 h = __float2bfloat16(f);   // rne
  u16 r; __builtin_memcpy(&r, &h, 2); return r;
}
__device__ __forceinline__ float sigmoid_f(float x){
  float e = __builtin_amdgcn_exp2f(-1.4426950408889634f * x);
  return __builtin_amdgcn_rcpf(1.0f + e);
}
__device__ __forceinline__ float tanh_f(float x){
  float ax = __builtin_fabsf(x);
  float e  = __builtin_amdgcn_exp2f(-2.8853900817779268f * ax);
  float t  = 1.0f - 2.0f * e * __builtin_amdgcn_rcpf(1.0f + e);
  return __builtin_copysignf(t, x);
}

// ---- pack weights into per-wave MFMA B-fragment order (bf16-hi only) ----
__global__ void prep_pack(const float* __restrict__ Wih_fw, const float* __restrict__ Whh_fw,
                          const float* __restrict__ Wih_bw, const float* __restrict__ Whh_bw,
                          u16* __restrict__ wsu)
{
  int idx = blockIdx.x*256 + threadIdx.x;       // grid exact: 2*DIR_U16/256 = 2304 blocks
  int d = idx / DIR_U16;
  int r = idx - d*DIR_U16;
  const float* Whh = d ? Whh_bw : Whh_fw;
  const float* Wih = d ? Wih_bw : Wih_fw;
  u16 outv;
  if (r < PK_HHD) {
    int e = r;
    int jj   = e & 7;
    int lane = (e >> 3) & 63;
    int kc   = (e >> 9) & 7;
    int gnt  = e >> 12;                // nt*3+g, < 48
    int g = gnt % 3, nt = gnt / 3;
    int row = g*256 + nt*16 + (lane & 15);
    int k   = kc*32 + ((lane >> 4) << 3) + jj;
    outv = f2bf(Whh[row*HHH + k]);
  } else {
    int e = r - PK_HHD;
    int jj   = e & 7;
    int lane = (e >> 3) & 63;
    int kc   = (e >> 9) & 3;
    int gnt  = e >> 11;                // < 48
    int g = gnt % 3, nt = gnt / 3;
    int row = g*256 + nt*16 + (lane & 15);
    int k   = kc*32 + ((lane >> 4) << 3) + jj;
    outv = f2bf(Wih[row*EE + k]);
  }
  wsu[idx] = outv;
}

// ---- bf16 embed table + fused biases ----
__global__ void prep_misc(const float* __restrict__ emb,
                          const float* __restrict__ bih_fw, const float* __restrict__ bhh_fw,
                          const float* __restrict__ bih_bw, const float* __restrict__ bhh_bw,
                          u16* __restrict__ wsu)
{
  int i = blockIdx.x*256 + threadIdx.x;
  if (i < EMB_U16) { wsu[EMB_OFF_U16 + i] = f2bf(emb[i]); return; }
  int b = i - EMB_U16;
  if (b >= 2048) return;
  int d = b >> 10, o = b & 1023;
  const float* bih = d ? bih_bw : bih_fw;
  const float* bhh = d ? bhh_bw : bhh_fw;
  float v;
  if (o < 512)      v = bih[o] + bhh[o];
  else if (o < 768) v = bih[o - 512 + 512];   // bih_n
  else              v = bhh[o - 768 + 512];   // bhh_n
  ((float*)(wsu + BIAS_OFF_U16))[d*1024 + o] = v;
}

__global__ __launch_bounds__(1024)
void gru_mfma(const int* __restrict__ chars, const int* __restrict__ chars_mask,
              const int* __restrict__ data_mask, const u16* __restrict__ wsu,
              float* __restrict__ out)
{
  // dir = blockIdx&1: with round-robin block->XCD (%8), every block on an XCD
  // shares one direction -> per-XCD weight working set ~0.6 MB.
  const int dir   = blockIdx.x & 1;
  const int word0 = (blockIdx.x >> 1) * MMW;
  const int j     = threadIdx.x;            // 0..1023 = 16 waves
  const int wave  = j >> 6, lane = j & 63;
  const int quad  = lane >> 4, l15 = lane & 15;

  const u16* wbase = wsu + (size_t)dir*DIR_U16;
  const bf16x8* pHH = (const bf16x8*)wbase;             // [(nt*3+g)*8+kc][64]
  const bf16x8* pIH = (const bf16x8*)(wbase + PK_HHD);  // [(nt*3+g)*4+kc][64]
  const u16*    embbf = wsu + EMB_OFF_U16;
  const float*  bias  = (const float*)(wsu + BIAS_OFF_U16) + dir*1024;

  // per-wave/lane fragment bases (this wave's gate-tile nt == wave)
  const bf16x8* bHH = pHH + (size_t)(wave*3)*8*64 + lane;
  const bf16x8* bIH = pIH + (size_t)(wave*3)*4*64 + lane;

  __shared__ __align__(16) u16   sh_hhi[MMW][264];    // bf16 hi of h, A-layout (33.8 KB)
  __shared__ __align__(16) u16   sh_hlo[MMW][264];    // bf16 lo of h          (33.8 KB)
  __shared__ __align__(16) u16   sh_x[MMW][136];      // x_t bf16              (17.4 KB)
  __shared__ float sh_m[MMW];

  for (int i = j; i < MMW*264; i += 1024) { (&sh_hhi[0][0])[i] = 0; (&sh_hlo[0][0])[i] = 0; }

  const int ch = wave*16 + l15;             // this lane's output channel
  const float bR  = bias[ch],        bZ  = bias[256 + ch];
  const float bXN = bias[512 + ch],  bHN = bias[768 + ch];

  const int sw = j >> 4, sp = j & 15;       // x-staging: word, 8-u16 part

  #pragma unroll 1
  for (int s = 0; s < CC; ++s) {
    const int t = dir ? (CC - 1 - s) : s;
    __syncthreads();                                   // S0: h writes visible, prev x reads done
    {
      int ci = chars[(word0 + sw)*CC + t];
      *(uint4*)&sh_x[sw][sp*8] = *(const uint4*)(embbf + (size_t)ci*EE + sp*8);
      if (j < MMW) sh_m[j] = (float)chars_mask[(word0 + j)*CC + t];
    }
    __syncthreads();                                   // S1: x/mask staged

    // acc[0]=r, acc[1]=z, acc[2]=xn, acc[3]=hn ; [m-tile 0..3]
    f32x4 acc[4][4];
    #pragma unroll
    for (int m = 0; m < 4; ++m) {
      acc[0][m] = (f32x4){bR,bR,bR,bR};
      acc[1][m] = (f32x4){bZ,bZ,bZ,bZ};
      acc[2][m] = (f32x4){bXN,bXN,bXN,bXN};
      acc[3][m] = (f32x4){bHN,bHN,bHN,bHN};
    }

    // ---- input projection: x(bf16) @ Wih^T, K=128 ----
    #pragma unroll
    for (int kc = 0; kc < 4; ++kc) {
      bf16x8 ax[4];
      #pragma unroll
      for (int m = 0; m < 4; ++m)
        ax[m] = *(const bf16x8*)&sh_x[m*16 + l15][kc*32 + quad*8];
      #pragma unroll
      for (int g = 0; g < 3; ++g) {
        bf16x8 b = bIH[(g*4 + kc)*64];
        const int ai = (g < 2) ? g : 2;
        #pragma unroll
        for (int m = 0; m < 4; ++m)
          acc[ai][m] = __builtin_amdgcn_mfma_f32_16x16x32_bf16(ax[m], b, acc[ai][m], 0,0,0);
      }
    }

    // ---- recurrence: (hhi+hlo) @ Whi^T, K=256 (h full-precision, W bf16) ----
    #pragma unroll
    for (int kc = 0; kc < 8; ++kc) {
      bf16x8 ah[4], al[4];
      #pragma unroll
      for (int m = 0; m < 4; ++m) {
        ah[m] = *(const bf16x8*)&sh_hhi[m*16 + l15][kc*32 + quad*8];
        al[m] = *(const bf16x8*)&sh_hlo[m*16 + l15][kc*32 + quad*8];
      }
      #pragma unroll
      for (int g = 0; g < 3; ++g) {
        bf16x8 bhi = bHH[(g*8 + kc)*64];
        const int ai = (g < 2) ? g : 3;
        #pragma unroll
        for (int m = 0; m < 4; ++m) {
          acc[ai][m] = __builtin_amdgcn_mfma_f32_16x16x32_bf16(ah[m], bhi, acc[ai][m], 0,0,0);
          acc[ai][m] = __builtin_amdgcn_mfma_f32_16x16x32_bf16(al[m], bhi, acc[ai][m], 0,0,0);
        }
      }
    }

    __syncthreads();                                   // S2: all h/x fragment reads done

    // ---- gate math + h update (lane owns (word, ch) pairs) ----
    #pragma unroll
    for (int m = 0; m < 4; ++m)
      #pragma unroll
      for (int r = 0; r < 4; ++r) {
        const int word = m*16 + quad*4 + r;
        float rr = sigmoid_f(acc[0][m][r]);
        float zz = sigmoid_f(acc[1][m][r]);
        float nn = tanh_f(fmaf(rr, acc[3][m][r], acc[2][m][r]));
        float hold = bf2f(sh_hhi[word][ch]) + bf2f(sh_hlo[word][ch]);
        float hnew = fmaf(zz, hold - nn, nn);              // (1-z)*n + z*h
        float hm   = fmaf(sh_m[word], hnew - hold, hold);  // mask freeze
        u16 hi = f2bf(hm);
        sh_hhi[word][ch] = hi;
        sh_hlo[word][ch] = f2bf(hm - bf2f(hi));
      }
  }
  __syncthreads();

  // ---- output: 64 words x 256 ch, 16 per thread, coalesced fp32 ----
  const int oc = j & 255, og = j >> 8;     // 4 groups of 16 words
  #pragma unroll
  for (int i = 0; i < 16; ++i) {
    const int w = og*16 + i;
    float dm = (float)data_mask[word0 + w];
    float h = bf2f(sh_hhi[w][oc]) + bf2f(sh_hlo[w][oc]);
    out[(size_t)(word0 + w)*(2*HHH) + dir*HHH + oc] = h * dm;
  }
}

extern "C" void kernel_launch(void* const* d_in, const int* in_sizes, int n_in,
                              void* d_out, int out_size, void* d_ws, size_t ws_size,
                              hipStream_t stream) {
  const int*   chars      = (const int*)d_in[0];
  const int*   chars_mask = (const int*)d_in[1];
  const int*   data_mask  = (const int*)d_in[2];
  const float* embed      = (const float*)d_in[3];
  const float* Wih_fw     = (const float*)d_in[4];
  const float* Whh_fw     = (const float*)d_in[5];
  const float* bih_fw     = (const float*)d_in[6];
  const float* bhh_fw     = (const float*)d_in[7];
  const float* Wih_bw     = (const float*)d_in[8];
  const float* Whh_bw     = (const float*)d_in[9];
  const float* bih_bw     = (const float*)d_in[10];
  const float* bhh_bw     = (const float*)d_in[11];
  u16* wsu = (u16*)d_ws;

  prep_pack<<<2*DIR_U16/256, 256, 0, stream>>>(Wih_fw, Whh_fw, Wih_bw, Whh_bw, wsu);
  prep_misc<<<(EMB_U16 + 2048 + 255)/256, 256, 0, stream>>>(embed, bih_fw, bhh_fw, bih_bw, bhh_bw, wsu);

  // 128 blocks: (word-group, dir) packed so dir == blockIdx&1
  gru_mfma<<<(NWORDS/MMW)*2, 1024, 0, stream>>>(chars, chars_mask, data_mask, wsu, (float*)d_out);
}